// Round 9
// baseline (324.153 us; speedup 1.0000x reference)
//
#include <hip/hip_runtime.h>

// TransformerConv x2 on MI355X — 32x32 MFMA GEMM (full-sector stores) +
// 16-lane gather attention over interleaved kv.
// N=50000, E=800000, H=4, C=32, D=128.

#define TPB 256

typedef __attribute__((ext_vector_type(8))) short short8v;
typedef __attribute__((ext_vector_type(8))) unsigned short ushort8v;
typedef __attribute__((ext_vector_type(16))) float f32x16;

__device__ __forceinline__ unsigned short f2bf(float f) {
    unsigned u = __float_as_uint(f);
    u = (u + 0x7FFFu + ((u >> 16) & 1u)) >> 16;
    return (unsigned short)u;
}
__device__ __forceinline__ float bf2f(unsigned short s) {
    return __uint_as_float((unsigned)s << 16);
}
__device__ __forceinline__ float exp2_hw(float x) {
    float r;
    asm("v_exp_f32 %0, %1" : "=v"(r) : "v"(x));
    return r;
}

// ---- fused: pack 8 weight matrices into 32x32-MFMA B-fragment layout,
//      plus fp32->bf16 convert of x (extra blocks) ----
__global__ void __launch_bounds__(TPB) prep_cvt_k(
    const float* __restrict__ Wq1, const float* __restrict__ Wk1,
    const float* __restrict__ Wv1, const float* __restrict__ Ws1,
    const float* __restrict__ Wq2, const float* __restrict__ Wk2,
    const float* __restrict__ Wv2, const float* __restrict__ Ws2,
    unsigned short* __restrict__ pack,
    const float* __restrict__ x, unsigned short* __restrict__ xb, int n4)
{
    if (blockIdx.x < 512) {
        int i = blockIdx.x * TPB + threadIdx.x;   // 131072 total
        // per g: idx = i & 16383: j=idx&7, lane=(idx>>3)&63, t=(idx>>9)&7, nc=(idx>>12)&3
        int j = i & 7, lane = (i >> 3) & 63, t = (i >> 9) & 7, nc = (i >> 12) & 3, g = (i >> 14) & 7;
        const float* Wt[8] = {Wq1, Wk1, Wv1, Ws1, Wq2, Wk2, Wv2, Ws2};
        const float* W = Wt[g];
        int kk = t * 16 + (lane >> 5) * 8 + j;
        int nn = nc * 32 + (lane & 31);
        pack[i] = f2bf(W[kk * 128 + nn]);
    } else {
        int i = (blockIdx.x - 512) * TPB + threadIdx.x;
        if (i >= n4) return;
        float4 v = *(const float4*)(x + (size_t)i * 4);
        ushort4 o;
        o.x = f2bf(v.x); o.y = f2bf(v.y); o.z = f2bf(v.z); o.w = f2bf(v.w);
        *(ushort4*)(xb + (size_t)i * 4) = o;
    }
}

// ---- MFMA GEMM (32x32x16): g=blockIdx.y: 0->q (stride 128), 1->kv k-half,
//      2->kv v-half (stride 256), 3->skip fp32.
__global__ void __launch_bounds__(TPB) gemm_mfma_k(
    const unsigned short* __restrict__ A, int M,
    const unsigned short* __restrict__ pack,
    const float* __restrict__ bq, const float* __restrict__ bk,
    const float* __restrict__ bv, const float* __restrict__ bs,
    unsigned short* __restrict__ oq, unsigned short* __restrict__ okv,
    float* __restrict__ os)
{
    const int g = blockIdx.y;
    const int row0 = blockIdx.x * 128;
    const int wv = threadIdx.x >> 6;
    const int lane = threadIdx.x & 63;
    const int rbase = row0 + wv * 32;
    const int arow = rbase + (lane & 31);
    const int kh = (lane >> 5) * 8;

    const short8v z8 = {0, 0, 0, 0, 0, 0, 0, 0};
    short8v a[8];
    if (arow < M) {
        const unsigned short* Ap = A + (size_t)arow * 128 + kh;
#pragma unroll
        for (int t = 0; t < 8; ++t) a[t] = *(const short8v*)(Ap + t * 16);
    } else {
#pragma unroll
        for (int t = 0; t < 8; ++t) a[t] = z8;
    }

    f32x16 acc[4];
#pragma unroll
    for (int nc = 0; nc < 4; ++nc)
#pragma unroll
        for (int r = 0; r < 16; ++r) acc[nc][r] = 0.f;

    const unsigned short* bp = pack + (size_t)g * 16384;
#pragma unroll
    for (int nc = 0; nc < 4; ++nc) {
#pragma unroll
        for (int t = 0; t < 8; ++t) {
            short8v b = *(const short8v*)(bp + (nc * 8 + t) * 512 + lane * 8);
            acc[nc] = __builtin_amdgcn_mfma_f32_32x32x16_bf16(a[t], b, acc[nc], 0, 0, 0);
        }
    }

    const float* bias = g == 0 ? bq : (g == 1 ? bk : (g == 2 ? bv : bs));
    const int col = lane & 31;
    const int rb2 = rbase + 4 * (lane >> 5);
    if (g == 3) {
#pragma unroll
        for (int nc = 0; nc < 4; ++nc) {
            float bb = bias[nc * 32 + col];
#pragma unroll
            for (int r = 0; r < 16; ++r) {
                int row = rb2 + (r & 3) + 8 * (r >> 2);
                if (row < M) os[(size_t)row * 128 + nc * 32 + col] = acc[nc][r] + bb;
            }
        }
    } else {
        unsigned short* out = g == 0 ? oq : okv;
        const int stride = g == 0 ? 128 : 256;
        const int goff = g == 2 ? 128 : 0;
#pragma unroll
        for (int nc = 0; nc < 4; ++nc) {
            float bb = bias[nc * 32 + col];
#pragma unroll
            for (int r = 0; r < 16; ++r) {
                int row = rb2 + (r & 3) + 8 * (r >> 2);
                if (row < M)
                    out[(size_t)row * stride + goff + nc * 32 + col] = f2bf(acc[nc][r] + bb);
            }
        }
    }
}

// ---------------- CSR build ----------------
__global__ void __launch_bounds__(TPB) hist_k(const int* __restrict__ dst,
                                              int* __restrict__ deg, int E)
{
    int e = blockIdx.x * TPB + threadIdx.x;
    if (e < E) atomicAdd(&deg[dst[e]], 1);
}

__global__ void __launch_bounds__(TPB) scan_a_k(const int* __restrict__ deg, int n,
                                                int* __restrict__ incl,
                                                int* __restrict__ bsum)
{
    __shared__ int ts[TPB];
    const int base = blockIdx.x * 1024;
    int vals[4], s = 0;
#pragma unroll
    for (int j = 0; j < 4; ++j) {
        int i = base + threadIdx.x * 4 + j;
        vals[j] = (i < n) ? deg[i] : 0;
        s += vals[j];
    }
    ts[threadIdx.x] = s;
    __syncthreads();
    for (int off = 1; off < TPB; off <<= 1) {
        int u = (threadIdx.x >= off) ? ts[threadIdx.x - off] : 0;
        __syncthreads();
        ts[threadIdx.x] += u;
        __syncthreads();
    }
    int run = ts[threadIdx.x] - s;
#pragma unroll
    for (int j = 0; j < 4; ++j) {
        run += vals[j];
        int i = base + threadIdx.x * 4 + j;
        if (i < n) incl[i] = run;
    }
    if (threadIdx.x == TPB - 1) bsum[blockIdx.x] = ts[TPB - 1];
}

__global__ void __launch_bounds__(TPB) scan_b_k(int* __restrict__ bsum, int nb)
{
    __shared__ int ts[TPB];
    int t = threadIdx.x;
    int v = (t < nb) ? bsum[t] : 0;
    ts[t] = v;
    __syncthreads();
    for (int off = 1; off < TPB; off <<= 1) {
        int u = (t >= off) ? ts[t - off] : 0;
        __syncthreads();
        ts[t] += u;
        __syncthreads();
    }
    if (t < nb) bsum[t] = ts[t] - v;
}

__global__ void __launch_bounds__(TPB) finalize_k(const int* __restrict__ incl,
                                                  const int* __restrict__ deg,
                                                  const int* __restrict__ bsum, int n,
                                                  int* __restrict__ row_ptr,
                                                  int* __restrict__ cursor)
{
    const int base = blockIdx.x * 1024;
    const int boff = bsum[blockIdx.x];
#pragma unroll
    for (int j = 0; j < 4; ++j) {
        int i = base + threadIdx.x * 4 + j;
        if (i < n) {
            int iv = incl[i] + boff;
            int st = iv - deg[i];
            row_ptr[i] = st;
            cursor[i] = st;
            if (i == n - 1) row_ptr[n] = iv;
        }
    }
}

__global__ void __launch_bounds__(TPB) scatter_k(
    const int* __restrict__ src, const int* __restrict__ dst,
    const float* __restrict__ ea, int* __restrict__ cursor,
    int2* __restrict__ csr_pair, int E)
{
    int e = blockIdx.x * TPB + threadIdx.x;
    if (e >= E) return;
    int pos = atomicAdd(&cursor[dst[e]], 1);
    csr_pair[pos] = make_int2(src[e], __float_as_int(ea[e]));
}

// ---- fused gather attention: 16 lanes/node, 4 nodes/wave, interleaved kv ----
template <bool BF16OUT>
__global__ void __launch_bounds__(TPB) node_attn_k(
    const unsigned short* __restrict__ q, const unsigned short* __restrict__ kv,
    const float* __restrict__ skip, const float* __restrict__ We,
    const int* __restrict__ row_ptr, const int2* __restrict__ csr_pair,
    void* __restrict__ outp, int n)
{
    const int node = blockIdx.x * 16 + (threadIdx.x >> 4);
    if (node >= n) return;
    const int l16 = threadIdx.x & 15;
    const int c8 = l16 * 8;

    const float C2 = 0.17677669529663687f * 1.44269504088896f; // 1/sqrt(32)*log2e

    float we8[8], qv[8];
    {
        float4 wlo = *(const float4*)(We + c8);
        float4 whi = *(const float4*)(We + c8 + 4);
        we8[0] = wlo.x; we8[1] = wlo.y; we8[2] = wlo.z; we8[3] = wlo.w;
        we8[4] = whi.x; we8[5] = whi.y; we8[6] = whi.z; we8[7] = whi.w;
        ushort8v qu = *(const ushort8v*)(q + (size_t)node * 128 + c8);
#pragma unroll
        for (int i = 0; i < 8; ++i) qv[i] = bf2f((unsigned short)qu[i]) * C2;
    }

    float qwe = 0.f;
#pragma unroll
    for (int i = 0; i < 8; ++i) qwe = fmaf(qv[i], we8[i], qwe);
    qwe += __shfl_xor(qwe, 1);
    qwe += __shfl_xor(qwe, 2);

    const int p0 = row_ptr[node], p1 = row_ptr[node + 1];

    float m = -3.4e38f, l = 0.f, sae = 0.f;
    float acc[8];
#pragma unroll
    for (int i = 0; i < 8; ++i) acc[i] = 0.f;

    for (int j = p0; j < p1; j += 4) {
        const int last = p1 - 1;
        int2 pr0 = csr_pair[j];
        int2 pr1 = csr_pair[min(j + 1, last)];
        int2 pr2 = csr_pair[min(j + 2, last)];
        int2 pr3 = csr_pair[min(j + 3, last)];
        const unsigned short* b0 = kv + (unsigned)pr0.x * 256u + c8;
        const unsigned short* b1 = kv + (unsigned)pr1.x * 256u + c8;
        const unsigned short* b2 = kv + (unsigned)pr2.x * 256u + c8;
        const unsigned short* b3 = kv + (unsigned)pr3.x * 256u + c8;
        ushort8v ku0 = *(const ushort8v*)b0;
        ushort8v ku1 = *(const ushort8v*)b1;
        ushort8v ku2 = *(const ushort8v*)b2;
        ushort8v ku3 = *(const ushort8v*)b3;
        ushort8v vu0 = *(const ushort8v*)(b0 + 128);
        ushort8v vu1 = *(const ushort8v*)(b1 + 128);
        ushort8v vu2 = *(const ushort8v*)(b2 + 128);
        ushort8v vu3 = *(const ushort8v*)(b3 + 128);

        float d0 = 0.f, d1 = 0.f, d2 = 0.f, d3 = 0.f;
#pragma unroll
        for (int i = 0; i < 8; ++i) {
            d0 = fmaf(bf2f((unsigned short)ku0[i]), qv[i], d0);
            d1 = fmaf(bf2f((unsigned short)ku1[i]), qv[i], d1);
            d2 = fmaf(bf2f((unsigned short)ku2[i]), qv[i], d2);
            d3 = fmaf(bf2f((unsigned short)ku3[i]), qv[i], d3);
        }
        d0 += __shfl_xor(d0, 1); d0 += __shfl_xor(d0, 2);
        d1 += __shfl_xor(d1, 1); d1 += __shfl_xor(d1, 2);
        d2 += __shfl_xor(d2, 1); d2 += __shfl_xor(d2, 2);
        d3 += __shfl_xor(d3, 1); d3 += __shfl_xor(d3, 2);

        float ea0 = __int_as_float(pr0.y), ea1 = __int_as_float(pr1.y);
        float ea2 = __int_as_float(pr2.y), ea3 = __int_as_float(pr3.y);
        float al0 = fmaf(ea0, qwe, d0);
        float al1 = (j + 1 < p1) ? fmaf(ea1, qwe, d1) : -3.4e38f;
        float al2 = (j + 2 < p1) ? fmaf(ea2, qwe, d2) : -3.4e38f;
        float al3 = (j + 3 < p1) ? fmaf(ea3, qwe, d3) : -3.4e38f;

        float mn = fmaxf(m, fmaxf(fmaxf(al0, al1), fmaxf(al2, al3)));
        float sc = exp2_hw(m - mn);
        float pe0 = exp2_hw(al0 - mn), pe1 = exp2_hw(al1 - mn);
        float pe2 = exp2_hw(al2 - mn), pe3 = exp2_hw(al3 - mn);

        l = fmaf(l, sc, (pe0 + pe1) + (pe2 + pe3));
        sae = fmaf(sae, sc, fmaf(pe3, ea3, fmaf(pe2, ea2, fmaf(pe1, ea1, pe0 * ea0))));
#pragma unroll
        for (int i = 0; i < 8; ++i) {
            float mv = fmaf(pe0, bf2f((unsigned short)vu0[i]),
                       fmaf(pe1, bf2f((unsigned short)vu1[i]),
                       fmaf(pe2, bf2f((unsigned short)vu2[i]),
                            pe3 * bf2f((unsigned short)vu3[i]))));
            acc[i] = fmaf(acc[i], sc, mv);
        }
        m = mn;
    }

    float inv = 1.f / (l + 1e-16f);
    float4 sklo = *(const float4*)(skip + (size_t)node * 128 + c8);
    float4 skhi = *(const float4*)(skip + (size_t)node * 128 + c8 + 4);
    float sk[8] = {sklo.x, sklo.y, sklo.z, sklo.w, skhi.x, skhi.y, skhi.z, skhi.w};
    float o[8];
#pragma unroll
    for (int i = 0; i < 8; ++i)
        o[i] = fmaxf(fmaf(fmaf(sae, we8[i], acc[i]), inv, sk[i]), 0.f);

    if (BF16OUT) {
        ushort8v ov;
#pragma unroll
        for (int i = 0; i < 8; ++i) ov[i] = f2bf(o[i]);
        *(ushort8v*)((unsigned short*)outp + (size_t)node * 128 + c8) = ov;
    } else {
        float* op = (float*)outp + (size_t)node * 128 + c8;
        *(float4*)op = make_float4(o[0], o[1], o[2], o[3]);
        *(float4*)(op + 4) = make_float4(o[4], o[5], o[6], o[7]);
    }
}

extern "C" void kernel_launch(void* const* d_in, const int* in_sizes, int n_in,
                              void* d_out, int out_size, void* d_ws, size_t ws_size,
                              hipStream_t stream)
{
    const float* x   = (const float*)d_in[0];
    const int*   ei  = (const int*)d_in[1];
    const float* ea  = (const float*)d_in[2];
    const float* Wq1 = (const float*)d_in[3];  const float* bq1 = (const float*)d_in[4];
    const float* Wk1 = (const float*)d_in[5];  const float* bk1 = (const float*)d_in[6];
    const float* Wv1 = (const float*)d_in[7];  const float* bv1 = (const float*)d_in[8];
    const float* We1 = (const float*)d_in[9];
    const float* Ws1 = (const float*)d_in[10]; const float* bs1 = (const float*)d_in[11];
    const float* Wq2 = (const float*)d_in[12]; const float* bq2 = (const float*)d_in[13];
    const float* Wk2 = (const float*)d_in[14]; const float* bk2 = (const float*)d_in[15];
    const float* Wv2 = (const float*)d_in[16]; const float* bv2 = (const float*)d_in[17];
    const float* We2 = (const float*)d_in[18];
    const float* Ws2 = (const float*)d_in[19]; const float* bs2 = (const float*)d_in[20];

    const int N = in_sizes[0] / 128;
    const int E = in_sizes[1] / 2;
    const int* src = ei;
    const int* dst = ei + E;
    float* outf = (float*)d_out;

    // workspace layout
    unsigned short* q  = (unsigned short*)d_ws;          // N*128 bf16
    unsigned short* kv = q + (size_t)N * 128;            // N*256 bf16 (k|v interleaved)
    float*          s  = (float*)(kv + (size_t)N * 256); // N*128 f32 skip
    unsigned short* xb = (unsigned short*)(s + (size_t)N * 128); // bf16 x / h
    unsigned short* pk = xb + (size_t)N * 128;           // 131072 (both layers)
    int*   row_ptr = (int*)(pk + 131072);                // N+1
    int*   deg     = row_ptr + (N + 1);
    int*   incl    = deg + N;
    int*   cursor  = incl + N;
    int*   bsum    = cursor + N;                         // 256
    int2*  csr_pair = (int2*)(((uintptr_t)(bsum + 256) + 7) & ~(uintptr_t)7); // E pairs

    const int gE   = (E + TPB - 1) / TPB;
    const int nb   = (N + 1023) / 1024;
    const int gN16 = (N + 15) / 16;
    const int n4   = N * 128 / 4;
    const int gPC  = 512 + (n4 + TPB - 1) / TPB;
    const int gG   = (N + 127) / 128;
    const dim3 gGd(gG, 4);

    // ---- CSR build (shared by both layers) ----
    hipMemsetAsync(deg, 0, (size_t)N * sizeof(int), stream);
    hist_k<<<gE, TPB, 0, stream>>>(dst, deg, E);
    scan_a_k<<<nb, TPB, 0, stream>>>(deg, N, incl, bsum);
    scan_b_k<<<1, TPB, 0, stream>>>(bsum, nb);
    finalize_k<<<nb, TPB, 0, stream>>>(incl, deg, bsum, N, row_ptr, cursor);
    scatter_k<<<gE, TPB, 0, stream>>>(src, dst, ea, cursor, csr_pair, E);

    // ---- weight prepack (both layers) + x convert ----
    prep_cvt_k<<<gPC, TPB, 0, stream>>>(Wq1, Wk1, Wv1, Ws1, Wq2, Wk2, Wv2, Ws2,
                                        pk, x, xb, n4);

    // ---- layer 1 ----
    gemm_mfma_k<<<gGd, TPB, 0, stream>>>(xb, N, pk, bq1, bk1, bv1, bs1, q, kv, s);
    node_attn_k<true><<<gN16, TPB, 0, stream>>>(q, kv, s, We1, row_ptr, csr_pair,
                                                xb, N);
    // ---- layer 2 ----
    gemm_mfma_k<<<gGd, TPB, 0, stream>>>(xb, N, pk + 65536, bq2, bk2, bv2, bs2,
                                         q, kv, s);
    node_attn_k<false><<<gN16, TPB, 0, stream>>>(q, kv, s, We2, row_ptr, csr_pair,
                                                 outf, N);
}